// Round 9
// baseline (256.176 us; speedup 1.0000x reference)
//
#include <hip/hip_runtime.h>
#include <hip/hip_fp16.h>

// GCN: h1 = relu(Agg(x@W1)+b1); h2 = relu(Agg(h1@W2)+b2); out = mean(h2)@Wc+bc
// norm(r,c)=dinv[r]*dinv[c] factors: GEMM epilogue prescales rows by dinv[r],
// agg sums raw fp16 rows and scales by dinv[c] at the end.
// R1: agg MLP (88->57). R2/R3/R4: scattered global atomics are a hard ~16 G/s
// ceiling (ILP/contention/scope all neutral-or-worse).
// R5: one atomic pass + bucket/gemm fusion (339). R6: interleave + fp16 hs (272).
// R7: zero-atomic CSR build (hist->colscan->rank-scatter fused w/ gemm1): 254.
// R8: (a) scatter LDS histogram initialized with chunk prefix => atomicAdd
//     returns the slot directly (kills 800k scattered pref reads); (b) dinv
//     prescale restored in GEMM epilogues (kills 800k deg gathers + rsqrts
//     per agg — deg is known before gemm1 since the build is atomic-free).

constexpr int N = 50000;
constexpr int E = 800000;
constexpr int D = 128;
constexpr int DOUT = 40;
constexpr int CAP = 64;               // slots/node (Poisson(16) tail ~1e-18)
constexpr int HB = 256;               // histogram chunks
constexpr int EPB = (E + HB - 1) / HB;     // 3125 edges/chunk
constexpr int HW = 12500;             // 50000 bytes = 12500 words
constexpr int GM = (N + 127) / 128;   // 391 gemm blocks
constexpr int NW = N / 4;             // 12500 agg blocks (exact: 4 nodes each)
constexpr int GF = 5 * 131;           // 655: 2/5 scatter (262>=256), 3/5 gemm (393>=391)

// ---------------- Phase A: per-chunk LDS histogram ----------------
__global__ __launch_bounds__(256) void k_hist(const int* __restrict__ col,
                                              unsigned char* __restrict__ hist) {
    __shared__ unsigned int h[HW];
    int b = blockIdx.x, t = threadIdx.x;
    for (int i = t; i < HW; i += 256) h[i] = 0;
    __syncthreads();
    int e0 = b * EPB, e1 = e0 + EPB;
    if (e1 > E) e1 = E;
    for (int e = e0 + t; e < e1; e += 256) {
        int c = col[e];
        atomicAdd(&h[c >> 2], 1u << ((c & 3) * 8));
    }
    __syncthreads();
    unsigned int* out = (unsigned int*)(hist + (size_t)b * 50000);
    for (int i = t; i < HW; i += 256) out[i] = h[i];
}

// ---------------- Phase B: per-node prefix over chunks; deg + dinv ---------
__global__ void k_colscan(unsigned char* __restrict__ hist, int* __restrict__ deg,
                          float* __restrict__ dinv) {
    int c = blockIdx.x * 256 + threadIdx.x;
    if (c >= N) return;
    int sum = 0;
#pragma unroll 8
    for (int b = 0; b < HB; ++b) {
        size_t idx = (size_t)b * 50000 + c;
        int v = hist[idx];
        hist[idx] = (unsigned char)sum;   // exclusive prefix (deg<=255 assumed)
        sum += v;
    }
    deg[c] = sum;
    dinv[c] = rsqrtf((float)(sum + 1));   // +1 self loop
}

// ---------------- shared GEMM tile: outH[r] = fp16(dinv[r] * (A[r] @ W)) ----
__device__ __forceinline__ float4 ld4(const float* p) { return *(const float4*)p; }
__device__ __forceinline__ float4 ld4(const __half* p) {
    uint2 u = *(const uint2*)p;
    __half2* h = (__half2*)&u;
    float2 a = __half22float2(h[0]), b = __half22float2(h[1]);
    return make_float4(a.x, a.y, b.x, b.y);
}

template <typename TA>
__device__ __forceinline__ void gemm128(const TA* __restrict__ A,
                                        const float* __restrict__ W,
                                        const float* __restrict__ dinv,
                                        __half* __restrict__ outH,
                                        int row0, int tid,
                                        float (*As)[132], float (*Bs)[132]) {
    int tx = tid & 15, ty = tid >> 4;
    float acc[8][8] = {};

    for (int kt = 0; kt < 128; kt += 32) {
        {
            int r = tid >> 1;
            int kk = (tid & 1) * 16;
            int grow = row0 + r;
#pragma unroll
            for (int q = 0; q < 4; ++q) {
                float4 v = make_float4(0.f, 0.f, 0.f, 0.f);
                if (grow < N) v = ld4(&A[(size_t)grow * D + kt + kk + q * 4]);
                As[kk + q * 4 + 0][r] = v.x;
                As[kk + q * 4 + 1][r] = v.y;
                As[kk + q * 4 + 2][r] = v.z;
                As[kk + q * 4 + 3][r] = v.w;
            }
        }
        {
            int kb = tid >> 3;
            int cb = (tid & 7) * 16;
#pragma unroll
            for (int q = 0; q < 4; ++q) {
                *(float4*)&Bs[kb][cb + q * 4] =
                    *(const float4*)&W[(size_t)(kt + kb) * D + cb + q * 4];
            }
        }
        __syncthreads();
#pragma unroll
        for (int k = 0; k < 32; ++k) {
            float a[8], bb[8];
            *(float4*)&a[0] = *(const float4*)&As[k][ty * 8];
            *(float4*)&a[4] = *(const float4*)&As[k][ty * 8 + 4];
            *(float4*)&bb[0] = *(const float4*)&Bs[k][tx * 4];
            *(float4*)&bb[4] = *(const float4*)&Bs[k][64 + tx * 4];
#pragma unroll
            for (int i = 0; i < 8; ++i)
#pragma unroll
                for (int j = 0; j < 8; ++j)
                    acc[i][j] = fmaf(a[i], bb[j], acc[i][j]);
        }
        __syncthreads();
    }

    // cols: j<4 -> tx*4+j ; j>=4 -> 64+tx*4+(j-4). Scale row by dinv[r].
#pragma unroll
    for (int i = 0; i < 8; ++i) {
        int r = row0 + ty * 8 + i;
        if (r < N) {
            float s = dinv[r];
            union { __half2 h[2]; uint2 u; } p0, p1;
            p0.h[0] = __floats2half2_rn(acc[i][0] * s, acc[i][1] * s);
            p0.h[1] = __floats2half2_rn(acc[i][2] * s, acc[i][3] * s);
            p1.h[0] = __floats2half2_rn(acc[i][4] * s, acc[i][5] * s);
            p1.h[1] = __floats2half2_rn(acc[i][6] * s, acc[i][7] * s);
            *(uint2*)&outH[(size_t)r * D + tx * 4]      = p0.u;
            *(uint2*)&outH[(size_t)r * D + 64 + tx * 4] = p1.u;
        }
    }
}

// ---------------- Phase C fused: rank-scatter + GEMM layer 1 ----------------
__global__ __launch_bounds__(256) void k_fuse(const int* __restrict__ ei,
                                              const unsigned char* __restrict__ hist,
                                              unsigned short* __restrict__ csr,
                                              const float* __restrict__ A,
                                              const float* __restrict__ W,
                                              const float* __restrict__ dinv,
                                              __half* __restrict__ outH) {
    __shared__ __align__(16) unsigned char smem[50048];  // max(50000, 2*32*132*4)
    int b = blockIdx.x, m = b % 5;

    if (m < 2) {
        // ---- scatter: LDS hist pre-loaded with chunk prefix => atomic = slot
        int sb = (b / 5) * 2 + m;
        if (sb >= HB) return;
        unsigned int* h = (unsigned int*)smem;
        const unsigned int* prefw = (const unsigned int*)(hist + (size_t)sb * 50000);
        int t = threadIdx.x;
        for (int i = t; i < HW; i += 256) h[i] = prefw[i];
        __syncthreads();
        int e0 = sb * EPB, e1 = e0 + EPB;
        if (e1 > E) e1 = E;
        for (int e = e0 + t; e < e1; e += 256) {
            int c = ei[E + e];
            int r = ei[e];
            unsigned int old = atomicAdd(&h[c >> 2], 1u << ((c & 3) * 8));
            int slot = (old >> ((c & 3) * 8)) & 0xff;
            if (slot < CAP) csr[(c << 6) + slot] = (unsigned short)r;
        }
        return;
    }
    // ---- gemm branch ----
    int gb = (b / 5) * 3 + (m - 2);
    if (gb >= GM) return;
    float (*As)[132] = (float (*)[132])smem;
    float (*Bs)[132] = (float (*)[132])(smem + 32 * 132 * 4);
    gemm128<float>(A, W, dinv, outH, gb * 128, threadIdx.x, As, Bs);
}

// ---------------- Plain GEMM (layer 2, fp16 A) ----------------
__global__ __launch_bounds__(256) void k_gemm(const __half* __restrict__ A,
                                              const float* __restrict__ W,
                                              const float* __restrict__ dinv,
                                              __half* __restrict__ outH) {
    __shared__ float As[32][132];
    __shared__ float Bs[32][132];
    gemm128<__half>(A, W, dinv, outH, blockIdx.x * 128, threadIdx.x, As, Bs);
}

// ---------------- Aggregation core (1 wave/node, fp16 row-sum) -------------
// Rows in hsH are pre-scaled by dinv[row]. a[8] = hsH[c] + sum_r hsH[r];
// caller applies dinv[c] and bias. Valid in qw==0 lanes after reduction.
__device__ __forceinline__ void add8(float* a, uint4 u) {
    __half2* hp = (__half2*)&u;
#pragma unroll
    for (int i = 0; i < 4; ++i) {
        float2 f = __half22float2(hp[i]);
        a[2 * i]     += f.x;
        a[2 * i + 1] += f.y;
    }
}

__device__ __forceinline__ float agg_core(int c, int lane,
                                          const __half* __restrict__ hsH,
                                          const int* __restrict__ deg,
                                          const unsigned short* __restrict__ csr,
                                          float* a0) {
    int qw = lane >> 4;         // 0..3: edge within group of 4
    int q  = lane & 15;         // column group: halves q*8..q*8+7
    int dgRaw = deg[c];
    int dg = dgRaw < CAP ? dgRaw : CAP;
    float dc = rsqrtf((float)(dgRaw + 1));
    int e0 = c << 6;

    float a1[8] = {0, 0, 0, 0, 0, 0, 0, 0};
#pragma unroll
    for (int t = 0; t < 8; ++t) a0[t] = 0.f;
    if (qw == 0)                // self loop (hsH[c] already = dinv[c]*h[c])
        add8(a0, *(const uint4*)&hsH[(size_t)c * D + q * 8]);

    int j = 0;
    for (; j + 8 <= dg; j += 8) {
        int r0 = csr[e0 + j + qw];
        int r1 = csr[e0 + j + 4 + qw];
        uint4 u0 = *(const uint4*)&hsH[(size_t)r0 * D + q * 8];
        uint4 u1 = *(const uint4*)&hsH[(size_t)r1 * D + q * 8];
        add8(a0, u0);
        add8(a1, u1);
    }
    if (j + 4 <= dg) {
        int r0 = csr[e0 + j + qw];
        add8(a0, *(const uint4*)&hsH[(size_t)r0 * D + q * 8]);
        j += 4;
    }
    int rem = dg - j;
    if (qw < rem) {
        int r0 = csr[e0 + j + qw];
        add8(a0, *(const uint4*)&hsH[(size_t)r0 * D + q * 8]);
    }

#pragma unroll
    for (int t = 0; t < 8; ++t) a0[t] += a1[t];
#pragma unroll
    for (int t = 0; t < 8; ++t) a0[t] += __shfl_xor(a0[t], 16, 64);
#pragma unroll
    for (int t = 0; t < 8; ++t) a0[t] += __shfl_xor(a0[t], 32, 64);
    return dc;
}

// layer-1 agg: writes fp16 rows (consumed by gemm2; NOT dinv-scaled — gemm2
// scales its own output)
__global__ __launch_bounds__(256) void k_agg1(const __half* __restrict__ hsH,
                                              const int* __restrict__ deg,
                                              const unsigned short* __restrict__ csr,
                                              const float* __restrict__ bias,
                                              __half* __restrict__ outH) {
    int wave = threadIdx.x >> 6;
    int lane = threadIdx.x & 63;
    int c = blockIdx.x * 4 + wave;          // grid exact: 12500*4 = 50000
    float a0[8];
    float dc = agg_core(c, lane, hsH, deg, csr, a0);
    if ((lane >> 4) == 0) {
        int q = lane & 15;
        union { __half2 h[4]; uint4 u; } p;
#pragma unroll
        for (int i = 0; i < 4; ++i) {
            float x = fmaxf(fmaf(dc, a0[2 * i],     bias[q * 8 + 2 * i]),     0.f);
            float y = fmaxf(fmaf(dc, a0[2 * i + 1], bias[q * 8 + 2 * i + 1]), 0.f);
            p.h[i] = __floats2half2_rn(x, y);
        }
        *(uint4*)&outH[(size_t)c * D + q * 8] = p.u;
    }
}

// layer-2 agg: reduces h2 rows straight into per-block pool partials
__global__ __launch_bounds__(256) void k_agg2(const __half* __restrict__ hsH,
                                              const int* __restrict__ deg,
                                              const unsigned short* __restrict__ csr,
                                              const float* __restrict__ bias,
                                              float* __restrict__ gpart) {
    __shared__ float gblk[4][128];
    int wave = threadIdx.x >> 6;
    int lane = threadIdx.x & 63;
    int c = blockIdx.x * 4 + wave;
    float a0[8];
    float dc = agg_core(c, lane, hsH, deg, csr, a0);
    if ((lane >> 4) == 0) {
        int q = lane & 15;
#pragma unroll
        for (int i = 0; i < 8; ++i)
            gblk[wave][q * 8 + i] = fmaxf(fmaf(dc, a0[i], bias[q * 8 + i]), 0.f);
    }
    __syncthreads();
    int t = threadIdx.x;
    if (t < 128)
        gpart[(size_t)blockIdx.x * 128 + t] =
            gblk[0][t] + gblk[1][t] + gblk[2][t] + gblk[3][t];
}

// ---------------- Pool stage 2: 12500 partials -> 256 partials --------------
__global__ __launch_bounds__(256) void k_pool(const float* __restrict__ gpart,
                                              float* __restrict__ gpart2) {
    int d = threadIdx.x & 127;
    int half = threadIdx.x >> 7;
    int b = blockIdx.x;                 // 256 blocks
    int per = (NW + 255) / 256;         // 49
    int r0 = b * per;
    int r1 = r0 + per;
    if (r1 > NW) r1 = NW;
    float acc = 0.f;
    for (int r = r0 + half; r < r1; r += 2)
        acc += gpart[(size_t)r * D + d];
    __shared__ float red[256];
    red[threadIdx.x] = acc;
    __syncthreads();
    if (half == 0) gpart2[(size_t)b * D + d] = red[d] + red[128 + d];
}

// ---------------- Final: g = sum(gpart2)/N; out = g@Wc + bc ----------------
__global__ __launch_bounds__(512) void k_final(const float* __restrict__ gpart2,
                                               const float* __restrict__ Wc,
                                               const float* __restrict__ bc,
                                               float* __restrict__ out) {
    __shared__ float g[D];
    __shared__ float red[512];
    int t = threadIdx.x;
    int d = t & 127, grp = t >> 7;      // 4 groups, 64 partials each
    float s = 0.f;
#pragma unroll 4
    for (int w = grp * 64; w < grp * 64 + 64; ++w)
        s += gpart2[(size_t)w * D + d];
    red[t] = s;
    __syncthreads();
    if (grp == 0)
        g[d] = (red[d] + red[128 + d] + red[256 + d] + red[384 + d]) * (1.0f / (float)N);
    __syncthreads();
    if (t < DOUT) {
        float acc = bc[t];
        for (int dd = 0; dd < D; ++dd) acc = fmaf(g[dd], Wc[dd * DOUT + t], acc);
        out[t] = acc;
    }
}

extern "C" void kernel_launch(void* const* d_in, const int* in_sizes, int n_in,
                              void* d_out, int out_size, void* d_ws, size_t ws_size,
                              hipStream_t stream) {
    const float* x  = (const float*)d_in[0];
    const int*   ei = (const int*)d_in[1];
    const float* W1 = (const float*)d_in[2];
    const float* b1 = (const float*)d_in[3];
    const float* W2 = (const float*)d_in[4];
    const float* b2 = (const float*)d_in[5];
    const float* Wc = (const float*)d_in[6];
    const float* bc = (const float*)d_in[7];
    float* out = (float*)d_out;

    char* ws = (char*)d_ws;
    size_t off = 0;
    auto alloc = [&](size_t bytes) {
        void* p = ws + off;
        off += (bytes + 511) & ~(size_t)511;
        return p;
    };
    unsigned char*  hist   = (unsigned char*) alloc((size_t)HB * 50000);     // 12.8MB
    int*            deg    = (int*)           alloc((size_t)N * 4);
    float*          dinv   = (float*)         alloc((size_t)N * 4);
    unsigned short* csr    = (unsigned short*)alloc((size_t)N * CAP * 2);    // 6.4MB
    __half*         hsH    = (__half*)        alloc((size_t)N * D * 2);      // 12.8MB
    __half*         hactH  = (__half*)        alloc((size_t)N * D * 2);      // 12.8MB
    float*          gpart  = (float*)         alloc((size_t)NW * D * 4);     // 6.4MB
    float*          gpart2 = (float*)         alloc((size_t)256 * D * 4);
    (void)ws_size; (void)in_sizes; (void)n_in; (void)out_size;

    const int* col = ei + E;

    // zero-atomic CSR build
    k_hist<<<HB, 256, 0, stream>>>(col, hist);
    k_colscan<<<(N + 255) / 256, 256, 0, stream>>>(hist, deg, dinv);
    // scatter (2/5) + gemm layer 1 (3/5), interleaved
    k_fuse<<<GF, 256, 0, stream>>>(ei, hist, csr, x, W1, dinv, hsH);

    // layer 1 aggregation -> fp16 rows (pre-relu'd, gemm2 scales by dinv)
    k_agg1<<<NW, 256, 0, stream>>>(hsH, deg, csr, b1, hactH);
    // layer 2 gemm (fp16 A) -> dinv-scaled fp16 rows
    k_gemm<<<GM, 256, 0, stream>>>(hactH, W2, dinv, hsH);
    // layer 2 aggregation -> pool partials
    k_agg2<<<NW, 256, 0, stream>>>(hsH, deg, csr, b2, gpart);
    // pool + classify
    k_pool<<<256, 256, 0, stream>>>(gpart, gpart2);
    k_final<<<1, 512, 0, stream>>>(gpart2, Wc, bc, out);
}